// Round 2
// baseline (5836.818 us; speedup 1.0000x reference)
//
#include <hip/hip_runtime.h>
#include <math.h>

// Problem constants (reference: B=8, N=4096, DIM=768, H=12, D=64, STAGES=3)
#define B_   8
#define N_   4096
#define DIM_ 768
#define H_   12
#define D_   64

// ---------------------------------------------------------------------------
// helpers
// ---------------------------------------------------------------------------
__device__ __forceinline__ float wave_sum(float v) {
  #pragma unroll
  for (int m = 32; m > 0; m >>= 1) v += __shfl_xor(v, m, 64);
  return v;
}

__device__ __forceinline__ float gelu_exact(float z) {
  // jax.nn.gelu(approximate=False) = 0.5*z*(1+erf(z/sqrt(2)))
  return 0.5f * z * (1.f + erff(z * 0.70710678118654752440f));
}

// ---------------------------------------------------------------------------
// 64x64x16-tiled fp32 GEMM, C = A(MxK) @ B(KxN)  [+bias / +fmap epilogue]
// mode 0: plain store, mode 1: elu(x)+1, mode 2: +bias[col]
// grid: (N/64, M/64), block 256
// ---------------------------------------------------------------------------
__global__ __launch_bounds__(256) void sgemm64(
    const float* __restrict__ A, const float* __restrict__ B,
    const float* __restrict__ bias, float* __restrict__ C,
    int M, int N, int K, int mode)
{
  __shared__ float As[16][64];
  __shared__ float Bs[16][64];
  const int tid = threadIdx.x;
  const int tx = tid & 15;      // col group (x4)
  const int ty = tid >> 4;      // row group (x4)
  const int row0 = blockIdx.y * 64;
  const int col0 = blockIdx.x * 64;

  const int ar = tid >> 2;           // 0..63  (A row within tile)
  const int ak = (tid & 3) * 4;      // 0,4,8,12 (A k within tile)
  const int bk = tid >> 4;           // 0..15  (B k within tile)
  const int bc = (tid & 15) * 4;     // 0..60  (B col within tile)

  const float* Ap = A + (long)(row0 + ar) * K + ak;
  const float* Bp = B + (long)bk * N + col0 + bc;

  float acc[4][4] = {};

  for (int k0 = 0; k0 < K; k0 += 16) {
    float4 av = *(const float4*)(Ap + k0);
    float4 bv = *(const float4*)(Bp + (long)k0 * N);
    As[ak + 0][ar] = av.x;
    As[ak + 1][ar] = av.y;
    As[ak + 2][ar] = av.z;
    As[ak + 3][ar] = av.w;
    *(float4*)&Bs[bk][bc] = bv;
    __syncthreads();
    #pragma unroll
    for (int kk = 0; kk < 16; ++kk) {
      float a_[4], b_[4];
      #pragma unroll
      for (int i = 0; i < 4; ++i) a_[i] = As[kk][ty * 4 + i];
      #pragma unroll
      for (int j = 0; j < 4; ++j) b_[j] = Bs[kk][tx * 4 + j];
      #pragma unroll
      for (int i = 0; i < 4; ++i)
        #pragma unroll
        for (int j = 0; j < 4; ++j)
          acc[i][j] += a_[i] * b_[j];
    }
    __syncthreads();
  }

  #pragma unroll
  for (int i = 0; i < 4; ++i) {
    const int r = row0 + ty * 4 + i;
    #pragma unroll
    for (int j = 0; j < 4; ++j) {
      const int c = col0 + tx * 4 + j;
      float vv = acc[i][j];
      if (mode == 1) vv = (vv > 0.f) ? (vv + 1.f) : expf(vv);   // elu(x)+1
      else if (mode == 2) vv += bias[c];
      C[(long)r * N + c] = vv;
    }
  }
}

// ---------------------------------------------------------------------------
// K-path pooling stage (single batch): t = mean(in[2n], in[2n+1]);
// out = gelu(LN(t@W + b)*g + be). One wave per output token; 4/block.
// Input addressed as in[h*h_stride + n*ts + d]; output [h][n_out][64].
// grid: H_*n_out/4
// ---------------------------------------------------------------------------
__global__ __launch_bounds__(256) void pool_k_mlp(
    const float* __restrict__ in, float* __restrict__ out, int n_out,
    int h_stride, int ts,
    const float* __restrict__ W, const float* __restrict__ bias,
    const float* __restrict__ g, const float* __restrict__ be)
{
  __shared__ float Ws[64 * 64];
  const int tid = threadIdx.x;
  for (int i = tid; i < 4096; i += 256) Ws[i] = W[i];
  __syncthreads();

  const int lane = tid & 63;
  const int gtok = blockIdx.x * 4 + (tid >> 6);
  const int n = gtok % n_out;
  const int h = gtok / n_out;

  const float* p0 = in + (long)h * h_stride + (long)(2 * n) * ts;
  float t = 0.5f * (p0[lane] + p0[ts + lane]);

  float acc = bias[lane];
  #pragma unroll
  for (int d = 0; d < 64; ++d)
    acc += __shfl(t, d, 64) * Ws[d * 64 + lane];

  const float mu  = wave_sum(acc) * 0.015625f;
  const float dv  = acc - mu;
  const float var = wave_sum(dv * dv) * 0.015625f;
  const float z   = dv * rsqrtf(var + 1e-5f) * g[lane] + be[lane];
  out[((long)h * n_out + n) * 64 + lane] = gelu_exact(z);
}

// ---------------------------------------------------------------------------
// V-path pooling (single batch): plain pairwise mean. Flat elementwise.
// grid: H_*n_out*64/256
// ---------------------------------------------------------------------------
__global__ __launch_bounds__(256) void pool_v_k(
    const float* __restrict__ in, float* __restrict__ out, int n_out,
    int h_stride, int ts)
{
  const long i = (long)blockIdx.x * 256 + threadIdx.x;
  const int d = (int)(i & 63);
  const long tok = i >> 6;
  const int n = (int)(tok % n_out);
  const int h = (int)(tok / n_out);
  const float* p = in + (long)h * h_stride + (long)(2 * n) * ts + d;
  out[((long)h * n_out + n) * 64 + d] = 0.5f * (p[0] + p[ts]);
}

// ---------------------------------------------------------------------------
// kv[h][d][e] = sum_n (kc[h][n][d]/sqrt(512)) * vc[h][n][e]
// ksum[h][d]  = sum_n  kc[h][n][d]/sqrt(512)
// grid = H_ (12), block 256; per-thread 16 outputs (col e = tid&63, rows dg*16+j)
// ---------------------------------------------------------------------------
__global__ __launch_bounds__(256) void kv_kernel(
    const float* __restrict__ kc, const float* __restrict__ vc,
    float* __restrict__ kv, float* __restrict__ ksum)
{
  __shared__ float ks[32 * 64];
  __shared__ float vs[32 * 64];
  const int tid = threadIdx.x;
  const int bh  = blockIdx.x;
  const float* kp = kc + (long)bh * 512 * 64;
  const float* vp = vc + (long)bh * 512 * 64;
  const float scale = 0.044194173824159216f;  // 1/sqrt(512)

  const int e  = tid & 63;
  const int dg = tid >> 6;  // 0..3 (wave id) -> rows dg*16 .. dg*16+15

  float acc[16] = {};
  float accs = 0.f;

  for (int n0 = 0; n0 < 512; n0 += 32) {
    float4 k0 = ((const float4*)(kp + (long)n0 * 64))[tid];
    float4 k1 = ((const float4*)(kp + (long)n0 * 64))[tid + 256];
    k0.x *= scale; k0.y *= scale; k0.z *= scale; k0.w *= scale;
    k1.x *= scale; k1.y *= scale; k1.z *= scale; k1.w *= scale;
    ((float4*)ks)[tid]       = k0;
    ((float4*)ks)[tid + 256] = k1;
    ((float4*)vs)[tid]       = ((const float4*)(vp + (long)n0 * 64))[tid];
    ((float4*)vs)[tid + 256] = ((const float4*)(vp + (long)n0 * 64))[tid + 256];
    __syncthreads();
    for (int nn = 0; nn < 32; ++nn) {
      const float vv = vs[nn * 64 + e];
      #pragma unroll
      for (int j = 0; j < 16; ++j)
        acc[j] += ks[nn * 64 + dg * 16 + j] * vv;  // broadcast within wave
      if (tid < 64) accs += ks[nn * 64 + tid];
    }
    __syncthreads();
  }

  float* kvo = kv + (long)bh * 4096;
  #pragma unroll
  for (int j = 0; j < 16; ++j)
    kvo[(dg * 16 + j) * 64 + e] = acc[j];
  if (tid < 64) ksum[bh * 64 + tid] = accs;
}

// ---------------------------------------------------------------------------
// out[n, h*64+e] = (sum_d q_d * kv[d][e]) / (sum_d q_d*ksum_d + 1e-6)
// q layout (n, h*64); grid (N_/4, H_); one wave per token.
// ---------------------------------------------------------------------------
__global__ __launch_bounds__(256) void attn_apply(
    const float* __restrict__ q, const float* __restrict__ kv,
    const float* __restrict__ ksum, float* __restrict__ out)
{
  __shared__ float kvs[4096];
  __shared__ float kss[64];
  const int tid = threadIdx.x;
  const int h   = blockIdx.y;
  const float4* kvg = (const float4*)(kv + (long)h * 4096);
  #pragma unroll
  for (int i = 0; i < 4; ++i) ((float4*)kvs)[tid + 256 * i] = kvg[tid + 256 * i];
  if (tid < 64) kss[tid] = ksum[h * 64 + tid];
  __syncthreads();

  const int lane = tid & 63;
  const int n = blockIdx.x * 4 + (tid >> 6);
  const float* qrow = q + (long)n * DIM_ + h * 64;
  const float qv = qrow[lane];
  const float den = wave_sum(qv * kss[lane]) + 1e-6f;
  float acc = 0.f;
  #pragma unroll
  for (int d = 0; d < 64; ++d)
    acc += __shfl(qv, d, 64) * kvs[d * 64 + lane];
  out[(long)n * DIM_ + h * 64 + lane] = acc / den;
}

// ---------------------------------------------------------------------------
// Expansion MLP, in-place on rows of 64: row = gelu(LN(row@W + b)*g + be)
// Buffer layout (n, h, 64) flat; one wave per (n,h) row. grid N_*H_/4
// ---------------------------------------------------------------------------
__global__ __launch_bounds__(256) void exp_mlp(
    float* __restrict__ buf,
    const float* __restrict__ W, const float* __restrict__ bias,
    const float* __restrict__ g, const float* __restrict__ be)
{
  __shared__ float Ws[64 * 64];
  const int tid = threadIdx.x;
  for (int i = tid; i < 4096; i += 256) Ws[i] = W[i];
  __syncthreads();

  const int lane = tid & 63;
  const int gtok = blockIdx.x * 4 + (tid >> 6);
  const int h  = gtok % H_;
  const int rn = gtok / H_;  // 0 .. N_-1
  float* row = buf + (long)rn * DIM_ + h * 64;

  const float t = row[lane];
  float acc = bias[lane];
  #pragma unroll
  for (int d = 0; d < 64; ++d)
    acc += __shfl(t, d, 64) * Ws[d * 64 + lane];

  const float mu  = wave_sum(acc) * 0.015625f;
  const float dv  = acc - mu;
  const float var = wave_sum(dv * dv) * 0.015625f;
  const float z   = dv * rsqrtf(var + 1e-5f) * g[lane] + be[lane];
  row[lane] = gelu_exact(z);
}

// ---------------------------------------------------------------------------
// launch — per-batch pipeline to keep workspace ~50 MB
// ---------------------------------------------------------------------------
extern "C" void kernel_launch(void* const* d_in, const int* in_sizes, int n_in,
                              void* d_out, int out_size, void* d_ws, size_t ws_size,
                              hipStream_t stream)
{
  const float* x   = (const float*)d_in[0];
  const float* Wq  = (const float*)d_in[1];
  const float* Wk  = (const float*)d_in[2];
  const float* Wv  = (const float*)d_in[3];
  const float* pW  = (const float*)d_in[4];
  const float* pb  = (const float*)d_in[5];
  const float* pg  = (const float*)d_in[6];
  const float* pbe = (const float*)d_in[7];
  const float* eW  = (const float*)d_in[8];
  const float* eb  = (const float*)d_in[9];
  const float* eg  = (const float*)d_in[10];
  const float* ebe = (const float*)d_in[11];
  const float* Wo  = (const float*)d_in[12];
  const float* bo  = (const float*)d_in[13];
  float* outp = (float*)d_out;

  // per-batch workspace layout (floats); reused every iteration
  const size_t SB = (size_t)N_ * DIM_;       // 3,145,728 floats per buffer
  float* ws   = (float*)d_ws;
  float* q    = ws;                          // (n, h*64)
  float* k    = q + SB;                      // (n, h*64); later attn_out
  float* v    = k + SB;                      // (n, h*64); later kc_b/vc_b
  float* kc_a = v + SB;                      // [12][2048][64]
  float* vc_a = kc_a + (size_t)H_ * 2048 * 64;
  float* kvb  = vc_a + (size_t)H_ * 2048 * 64;   // [12][64][64]
  float* ksum = kvb + (size_t)H_ * 64 * 64;      // [12][64]
  float* end  = ksum + H_ * 64;
  float* kc_b = v;                           // alias: v consumed after stage 0
  float* vc_b = v + (size_t)H_ * 1024 * 64;
  float* attn_out = k;                       // alias: k consumed after stage 0

  const size_t need_bytes = (size_t)(end - ws) * sizeof(float);
  if (ws_size < need_bytes) return;  // ~50.5 MB required

  const dim3 gg(DIM_ / 64, N_ / 64);
  for (int b = 0; b < B_; ++b) {
    const float* xb = x + (size_t)b * SB;
    float* ob = outp + (size_t)b * SB;

    // projections (fmap fused for q,k)
    sgemm64<<<gg, 256, 0, stream>>>(xb, Wq, nullptr, q, N_, DIM_, DIM_, 1);
    sgemm64<<<gg, 256, 0, stream>>>(xb, Wk, nullptr, k, N_, DIM_, DIM_, 1);
    sgemm64<<<gg, 256, 0, stream>>>(xb, Wv, nullptr, v, N_, DIM_, DIM_, 0);

    // pooling stage 0: 4096 -> 2048 (reads k/v in (n,h,d) layout)
    pool_k_mlp<<<H_ * 2048 / 4, 256, 0, stream>>>(k, kc_a, 2048, 64, DIM_,
                                                  pW, pb, pg, pbe);
    pool_v_k<<<H_ * 2048 * 64 / 256, 256, 0, stream>>>(v, vc_a, 2048, 64, DIM_);
    // stage 1: 2048 -> 1024 ([h][n][64] layout)
    pool_k_mlp<<<H_ * 1024 / 4, 256, 0, stream>>>(kc_a, kc_b, 1024, 2048 * 64, 64,
                                                  pW + 4096, pb + 64, pg + 64, pbe + 64);
    pool_v_k<<<H_ * 1024 * 64 / 256, 256, 0, stream>>>(vc_a, vc_b, 1024, 2048 * 64, 64);
    // stage 2: 1024 -> 512
    pool_k_mlp<<<H_ * 512 / 4, 256, 0, stream>>>(kc_b, kc_a, 512, 1024 * 64, 64,
                                                 pW + 8192, pb + 128, pg + 128, pbe + 128);
    pool_v_k<<<H_ * 512 * 64 / 256, 256, 0, stream>>>(vc_b, vc_a, 512, 1024 * 64, 64);

    // kv contraction + ksum
    kv_kernel<<<H_, 256, 0, stream>>>(kc_a, vc_a, kvb, ksum);

    // out = (q @ kv) / (q . ksum + 1e-6), written in (n,h,d) layout
    attn_apply<<<dim3(N_ / 4, H_), 256, 0, stream>>>(q, kvb, ksum, attn_out);

    // expansion MLPs, reversed stage order, in-place
    for (int i = 2; i >= 0; --i)
      exp_mlp<<<(N_ * H_) / 4, 256, 0, stream>>>(attn_out, eW + i * 4096,
                                                 eb + i * 64, eg + i * 64,
                                                 ebe + i * 64);

    // final projection + bias
    sgemm64<<<gg, 256, 0, stream>>>(attn_out, Wo, bo, ob, N_, DIM_, DIM_, 2);
  }
}

// Round 3
// 3199.666 us; speedup vs baseline: 1.8242x; 1.8242x over previous
//
#include <hip/hip_runtime.h>
#include <math.h>

#define B_   8
#define N_   4096
#define DIM_ 768
#define H_   12
#define D_   64

typedef unsigned short ushort_t;
typedef __attribute__((ext_vector_type(8))) short short8;
typedef __attribute__((ext_vector_type(4))) float f32x4;

// ---------------------------------------------------------------------------
// helpers
// ---------------------------------------------------------------------------
__device__ __forceinline__ float wave_sum(float v) {
  #pragma unroll
  for (int m = 32; m > 0; m >>= 1) v += __shfl_xor(v, m, 64);
  return v;
}

__device__ __forceinline__ float gelu_exact(float z) {
  return 0.5f * z * (1.f + erff(z * 0.70710678118654752440f));
}

__device__ __forceinline__ ushort_t f2bf(float f) {
  union { float f; unsigned u; } x; x.f = f;
  unsigned r = x.u + 0x7FFFu + ((x.u >> 16) & 1u);   // RNE
  return (ushort_t)(r >> 16);
}

__device__ __forceinline__ float bf2f(ushort_t h) {
  union { unsigned u; float f; } x; x.u = ((unsigned)h) << 16;
  return x.f;
}

__device__ __forceinline__ void gl_lds16(const ushort_t* g, ushort_t* l) {
  // async global->LDS, 16B per lane; LDS dest = wave-uniform base + lane*16
  __builtin_amdgcn_global_load_lds(
      (const __attribute__((address_space(1))) void*)g,
      (__attribute__((address_space(3))) void*)l, 16, 0, 0);
}

// ---------------------------------------------------------------------------
// 768x768 fp32 -> bf16 transposed copy (dst[n][k] = src[k][n])
// block 256 (32x8), grid (24,24)
// ---------------------------------------------------------------------------
__global__ __launch_bounds__(256) void transpose_w_bf16(
    const float* __restrict__ src, ushort_t* __restrict__ dst)
{
  __shared__ float t[32][33];
  const int lx = threadIdx.x & 31, ly = threadIdx.x >> 5;
  const int bx = blockIdx.x * 32;   // n
  const int by = blockIdx.y * 32;   // k
  #pragma unroll
  for (int j = 0; j < 32; j += 8)
    t[ly + j][lx] = src[(size_t)(by + ly + j) * 768 + bx + lx];
  __syncthreads();
  #pragma unroll
  for (int j = 0; j < 32; j += 8)
    dst[(size_t)(bx + ly + j) * 768 + by + lx] = f2bf(t[lx][ly + j]);
}

// ---------------------------------------------------------------------------
// fp32 -> bf16 flat convert (n4 float4 groups)
// ---------------------------------------------------------------------------
__global__ __launch_bounds__(256) void conv_f32_bf16(
    const float* __restrict__ src, ushort_t* __restrict__ dst)
{
  const int i = blockIdx.x * 256 + threadIdx.x;
  float4 f = ((const float4*)src)[i];
  ushort4 o;
  o.x = f2bf(f.x); o.y = f2bf(f.y); o.z = f2bf(f.z); o.w = f2bf(f.w);
  ((ushort4*)dst)[i] = o;
}

// ---------------------------------------------------------------------------
// bf16 MFMA GEMM mainloop: C(128x128) = A(M x K) @ Bt(N x K)^T
// tile 128x128, BK=32, 256 thr = 4 waves (2x2), each wave 4x4 16x16 tiles.
// ---------------------------------------------------------------------------
#define GEMM_MAINLOOP(A, Bt, K)                                               \
  __shared__ ushort_t As[128 * 32];                                           \
  __shared__ ushort_t Bs[128 * 32];                                           \
  const int tid = threadIdx.x;                                                \
  const int row0 = blockIdx.y * 128;                                          \
  const int col0 = blockIdx.x * 128;                                          \
  const int sr = tid >> 2;                                                    \
  const int sk = (tid & 3) * 8;                                               \
  const ushort_t* Ag0 = (A) + (size_t)(row0 + sr) * (K) + sk;                 \
  const ushort_t* Ag1 = Ag0 + (size_t)64 * (K);                               \
  const ushort_t* Bg0 = (Bt) + (size_t)(col0 + sr) * (K) + sk;                \
  const ushort_t* Bg1 = Bg0 + (size_t)64 * (K);                               \
  ushort_t* Asw = As + (tid >> 6) * 512;                                      \
  ushort_t* Bsw = Bs + (tid >> 6) * 512;                                      \
  const int w = tid >> 6, lane = tid & 63;                                    \
  const int wm = w >> 1, wn = w & 1;                                          \
  const int qd = lane >> 4, l15 = lane & 15;                                  \
  const int aoff = (wm * 64 + l15) * 32 + qd * 8;                             \
  const int boff = (wn * 64 + l15) * 32 + qd * 8;                             \
  f32x4 acc[4][4] = {};                                                       \
  for (int k0 = 0; k0 < (K); k0 += 32) {                                      \
    __syncthreads();                                                          \
    gl_lds16(Ag0 + k0, Asw);                                                  \
    gl_lds16(Ag1 + k0, Asw + 2048);                                           \
    gl_lds16(Bg0 + k0, Bsw);                                                  \
    gl_lds16(Bg1 + k0, Bsw + 2048);                                           \
    __syncthreads();                                                          \
    short8 af[4], bfr[4];                                                     \
    _Pragma("unroll")                                                         \
    for (int mt = 0; mt < 4; ++mt) af[mt] = *(const short8*)&As[aoff + mt * 512]; \
    _Pragma("unroll")                                                         \
    for (int nt = 0; nt < 4; ++nt) bfr[nt] = *(const short8*)&Bs[boff + nt * 512]; \
    _Pragma("unroll")                                                         \
    for (int mt = 0; mt < 4; ++mt)                                            \
      _Pragma("unroll")                                                       \
      for (int nt = 0; nt < 4; ++nt)                                          \
        acc[mt][nt] = __builtin_amdgcn_mfma_f32_16x16x32_bf16(                \
            af[mt], bfr[nt], acc[mt][nt], 0, 0, 0);                           \
  }

// QKV GEMM: A = x bf16 (4096x768), Bt = WqkvT bf16 (2304x768).
// Epilogue routes by column block: [0,768)->q bf16 elu+1, [768,1536)->k f32
// elu+1, [1536,2304)->v f32. grid (18, 32).
__global__ __launch_bounds__(256) void gemm_qkv(
    const ushort_t* __restrict__ A, const ushort_t* __restrict__ Bt,
    ushort_t* __restrict__ qo, float* __restrict__ ko, float* __restrict__ vo)
{
  GEMM_MAINLOOP(A, Bt, 768)
  const int sel = col0 / 768;               // 128-tiles never straddle
  const int colbase = (col0 % 768) + wn * 64;
  #pragma unroll
  for (int mt = 0; mt < 4; ++mt) {
    #pragma unroll
    for (int nt = 0; nt < 4; ++nt) {
      const int cg = colbase + nt * 16 + l15;
      #pragma unroll
      for (int r = 0; r < 4; ++r) {
        const int rg = row0 + wm * 64 + mt * 16 + qd * 4 + r;
        const float vv = acc[mt][nt][r];
        if (sel == 0) {
          const float e = (vv > 0.f) ? vv + 1.f : expf(vv);
          qo[(size_t)rg * 768 + cg] = f2bf(e);
        } else if (sel == 1) {
          ko[(size_t)rg * 768 + cg] = (vv > 0.f) ? vv + 1.f : expf(vv);
        } else {
          vo[(size_t)rg * 768 + cg] = vv;
        }
      }
    }
  }
}

// Output GEMM: C = A(4096x768) @ WoT^T + bo. grid (6, 32).
__global__ __launch_bounds__(256) void gemm_out(
    const ushort_t* __restrict__ A, const ushort_t* __restrict__ Bt,
    const float* __restrict__ bo, float* __restrict__ C)
{
  GEMM_MAINLOOP(A, Bt, 768)
  #pragma unroll
  for (int mt = 0; mt < 4; ++mt) {
    #pragma unroll
    for (int nt = 0; nt < 4; ++nt) {
      const int cg = col0 + wn * 64 + nt * 16 + l15;
      #pragma unroll
      for (int r = 0; r < 4; ++r) {
        const int rg = row0 + wm * 64 + mt * 16 + qd * 4 + r;
        C[(size_t)rg * 768 + cg] = acc[mt][nt][r] + bo[cg];
      }
    }
  }
}

// ---------------------------------------------------------------------------
// K-path pooling: t = mean(in[2n], in[2n+1]); out = gelu(LN(t@W+b)*g+be)
// one wave per output token, 4/block. in[h*h_stride + n*ts + d], out [h][n][64]
// ---------------------------------------------------------------------------
__global__ __launch_bounds__(256) void pool_k_mlp(
    const float* __restrict__ in, float* __restrict__ out, int n_out,
    int h_stride, int ts,
    const float* __restrict__ W, const float* __restrict__ bias,
    const float* __restrict__ g, const float* __restrict__ be)
{
  __shared__ float Ws[64 * 64];
  const int tid = threadIdx.x;
  for (int i = tid; i < 4096; i += 256) Ws[i] = W[i];
  __syncthreads();

  const int lane = tid & 63;
  const int gtok = blockIdx.x * 4 + (tid >> 6);
  const int n = gtok % n_out;
  const int h = gtok / n_out;

  const float* p0 = in + (size_t)h * h_stride + (size_t)(2 * n) * ts;
  const float t = 0.5f * (p0[lane] + p0[ts + lane]);

  float acc = bias[lane];
  #pragma unroll
  for (int d = 0; d < 64; ++d)
    acc += __shfl(t, d, 64) * Ws[d * 64 + lane];

  const float mu  = wave_sum(acc) * 0.015625f;
  const float dv  = acc - mu;
  const float var = wave_sum(dv * dv) * 0.015625f;
  const float z   = dv * rsqrtf(var + 1e-5f) * g[lane] + be[lane];
  out[((size_t)h * n_out + n) * 64 + lane] = gelu_exact(z);
}

// ---------------------------------------------------------------------------
// V-path: 3 pairwise means == mean of 8 consecutive tokens (no MLP on v).
// in (n, 768) f32 -> out [12][512][64]. grid 12*512*64/256 = 1536.
// ---------------------------------------------------------------------------
__global__ __launch_bounds__(256) void avgpool8_v(
    const float* __restrict__ v, float* __restrict__ out)
{
  const int idx = blockIdx.x * 256 + threadIdx.x;
  const int e = idx & 63;
  const int n = (idx >> 6) & 511;
  const int h = idx >> 15;
  const float* p = v + (size_t)(8 * n) * 768 + h * 64 + e;
  float s = 0.f;
  #pragma unroll
  for (int j = 0; j < 8; ++j) s += p[(size_t)j * 768];
  out[idx] = 0.125f * s;
}

// ---------------------------------------------------------------------------
// kv partials: grid (12 heads, 16 chunks of 32 tokens), block 256.
// kvp[(h*16+c)*4096 + d*64+e] = sum_n kc[n][d]*vc[n][e] (unscaled)
// ---------------------------------------------------------------------------
__global__ __launch_bounds__(256) void kv_part_kernel(
    const float* __restrict__ kc, const float* __restrict__ vc,
    float* __restrict__ kvp, float* __restrict__ ksp)
{
  __shared__ float ks[32 * 64];
  __shared__ float vs[32 * 64];
  const int tid = threadIdx.x;
  const int h = blockIdx.x;
  const int c = blockIdx.y;
  const float* kp = kc + ((size_t)h * 512 + c * 32) * 64;
  const float* vp = vc + ((size_t)h * 512 + c * 32) * 64;
  ((float4*)ks)[tid]       = ((const float4*)kp)[tid];
  ((float4*)ks)[tid + 256] = ((const float4*)kp)[tid + 256];
  ((float4*)vs)[tid]       = ((const float4*)vp)[tid];
  ((float4*)vs)[tid + 256] = ((const float4*)vp)[tid + 256];
  __syncthreads();

  const int e = tid & 63;
  const int dg = tid >> 6;
  float acc[16] = {};
  float accs = 0.f;
  for (int nn = 0; nn < 32; ++nn) {
    const float vv = vs[nn * 64 + e];
    #pragma unroll
    for (int j = 0; j < 16; ++j)
      acc[j] += ks[nn * 64 + dg * 16 + j] * vv;
    if (tid < 64) accs += ks[nn * 64 + tid];
  }
  float* o = kvp + ((size_t)h * 16 + c) * 4096;
  #pragma unroll
  for (int j = 0; j < 16; ++j)
    o[(dg * 16 + j) * 64 + e] = acc[j];
  if (tid < 64) ksp[(h * 16 + c) * 64 + tid] = accs;
}

__global__ __launch_bounds__(256) void kv_reduce(
    const float* __restrict__ kvp, const float* __restrict__ ksp,
    float* __restrict__ kvb, float* __restrict__ ksum)
{
  const int idx = blockIdx.x * 256 + threadIdx.x;
  const float scale = 0.044194173824159216f;  // 1/sqrt(512)
  if (idx < 12 * 4096) {
    const int h = idx >> 12, de = idx & 4095;
    float s = 0.f;
    #pragma unroll
    for (int c = 0; c < 16; ++c) s += kvp[((size_t)h * 16 + c) * 4096 + de];
    kvb[idx] = s * scale;
  } else if (idx < 12 * 4096 + 768) {
    const int j = idx - 12 * 4096;
    float s = 0.f;
    #pragma unroll
    for (int c = 0; c < 16; ++c) s += ksp[((j >> 6) * 16 + c) * 64 + (j & 63)];
    ksum[j] = s * scale;
  }
}

// ---------------------------------------------------------------------------
// Fused: out_row = q@kv / (q.ksum+1e-6), then 3 expansion MLPs (s=2,1,0).
// grid (N/4, 12); one wave per token. LDS = kv tile (16KB) + 3 W mats (48KB).
// ---------------------------------------------------------------------------
__global__ __launch_bounds__(256) void attn_exp(
    const ushort_t* __restrict__ q16, const float* __restrict__ kvb,
    const float* __restrict__ ksum,
    const float* __restrict__ eW, const float* __restrict__ eb,
    const float* __restrict__ eg, const float* __restrict__ ebe,
    float* __restrict__ out)
{
  __shared__ float smem[16384];          // [0,4096)=kv, [4096,16384)=3x W
  float* kvs = smem;
  float* Ws  = smem + 4096;
  const int tid = threadIdx.x;
  const int h = blockIdx.y;
  {
    const float4* src = (const float4*)(kvb + (size_t)h * 4096);
    #pragma unroll
    for (int i = 0; i < 4; ++i) ((float4*)kvs)[tid + 256 * i] = src[tid + 256 * i];
    const float4* ew4 = (const float4*)eW;
    #pragma unroll
    for (int i = 0; i < 12; ++i) ((float4*)Ws)[tid + 256 * i] = ew4[tid + 256 * i];
  }
  __syncthreads();

  const int lane = tid & 63;
  const int n = blockIdx.x * 4 + (tid >> 6);
  const float ks_l = ksum[h * 64 + lane];
  const float qv = bf2f(q16[(size_t)n * 768 + h * 64 + lane]);
  const float den = wave_sum(qv * ks_l) + 1e-6f;
  float acc = 0.f;
  #pragma unroll
  for (int d = 0; d < 64; ++d)
    acc += __shfl(qv, d, 64) * kvs[d * 64 + lane];
  float t = acc / den;

  #pragma unroll
  for (int s = 2; s >= 0; --s) {
    float a = eb[s * 64 + lane];
    const float* W = Ws + s * 4096;
    #pragma unroll
    for (int d = 0; d < 64; ++d)
      a += __shfl(t, d, 64) * W[d * 64 + lane];
    const float mu  = wave_sum(a) * 0.015625f;
    const float dv  = a - mu;
    const float var = wave_sum(dv * dv) * 0.015625f;
    const float z   = dv * rsqrtf(var + 1e-5f) * eg[s * 64 + lane] + ebe[s * 64 + lane];
    t = gelu_exact(z);
  }
  out[(size_t)n * 768 + h * 64 + lane] = t;
}

// ---------------------------------------------------------------------------
// launch
// ---------------------------------------------------------------------------
extern "C" void kernel_launch(void* const* d_in, const int* in_sizes, int n_in,
                              void* d_out, int out_size, void* d_ws, size_t ws_size,
                              hipStream_t stream)
{
  const float* x   = (const float*)d_in[0];
  const float* Wq  = (const float*)d_in[1];
  const float* Wk  = (const float*)d_in[2];
  const float* Wv  = (const float*)d_in[3];
  const float* pW  = (const float*)d_in[4];
  const float* pb  = (const float*)d_in[5];
  const float* pg  = (const float*)d_in[6];
  const float* pbe = (const float*)d_in[7];
  const float* eW  = (const float*)d_in[8];
  const float* eb  = (const float*)d_in[9];
  const float* eg  = (const float*)d_in[10];
  const float* ebe = (const float*)d_in[11];
  const float* Wo  = (const float*)d_in[12];
  const float* bo  = (const float*)d_in[13];
  float* outp = (float*)d_out;

  // ---- workspace map (bytes) ----
  unsigned char* wsb = (unsigned char*)d_ws;
  ushort_t* WqkvT = (ushort_t*)(wsb + 0);              // 2304x768 bf16 = 3,538,944
  ushort_t* WoT   = (ushort_t*)(wsb + 3538944);        // 768x768 bf16  = 1,179,648
  ushort_t* q16   = (ushort_t*)(wsb + 4718592);        // 4096x768 bf16 = 6,291,456
  unsigned char* XB = wsb + 11010048;                  // xb16 / kc_a   = 6,291,456
  float* kbuf = (float*)(wsb + 17301504);              // k / attn_out  = 12,582,912
  float* vbuf = (float*)(wsb + 29884416);              // v / kc_b,kc_c / ao16
  float* vc   = (float*)(wsb + 42467328);              // [12][512][64] = 1,572,864
  float* kvp  = (float*)(wsb + 44040192);              // 12*16*4096 f32= 3,145,728
  float* ksp  = (float*)(wsb + 47185920);              // 12*16*64 f32  = 49,152
  float* kvb  = (float*)(wsb + 47235072);              // 12*4096 f32   = 196,608
  float* ksum = (float*)(wsb + 47431680);              // 768 f32       = 3,072
  const size_t need = 47434752;
  if (ws_size < need) return;

  ushort_t* xb16 = (ushort_t*)XB;
  float* kc_a = (float*)XB;                            // [12][2048][64]
  float* kc_b = vbuf;                                  // [12][1024][64]
  float* kc_c = (float*)((unsigned char*)vbuf + 3145728); // [12][512][64]
  ushort_t* ao16 = (ushort_t*)vbuf;

  const size_t SB = (size_t)N_ * DIM_;

  // one-time: weight transpose + bf16 convert
  transpose_w_bf16<<<dim3(24, 24), 256, 0, stream>>>(Wq, WqkvT);
  transpose_w_bf16<<<dim3(24, 24), 256, 0, stream>>>(Wk, WqkvT + 768 * 768);
  transpose_w_bf16<<<dim3(24, 24), 256, 0, stream>>>(Wv, WqkvT + 2 * 768 * 768);
  transpose_w_bf16<<<dim3(24, 24), 256, 0, stream>>>(Wo, WoT);

  for (int b = 0; b < B_; ++b) {
    const float* xb = x + (size_t)b * SB;
    float* ob = outp + (size_t)b * SB;

    // x -> bf16
    conv_f32_bf16<<<(int)(SB / 4 / 256), 256, 0, stream>>>(xb, xb16);
    // fused QKV projection (q bf16 elu+1, k f32 elu+1, v f32)
    gemm_qkv<<<dim3(18, 32), 256, 0, stream>>>(xb16, WqkvT, q16, kbuf, vbuf);

    // v-path: one-shot avgpool of 8
    avgpool8_v<<<1536, 256, 0, stream>>>(vbuf, vc);
    // k-path: 3 pooling+MLP stages
    pool_k_mlp<<<H_ * 2048 / 4, 256, 0, stream>>>(kbuf, kc_a, 2048, 64, 768,
                                                  pW, pb, pg, pbe);
    pool_k_mlp<<<H_ * 1024 / 4, 256, 0, stream>>>(kc_a, kc_b, 1024, 2048 * 64, 64,
                                                  pW + 4096, pb + 64, pg + 64, pbe + 64);
    pool_k_mlp<<<H_ * 512 / 4, 256, 0, stream>>>(kc_b, kc_c, 512, 1024 * 64, 64,
                                                 pW + 8192, pb + 128, pg + 128, pbe + 128);

    // kv contraction (split over 16 chunks) + reduce
    kv_part_kernel<<<dim3(12, 16), 256, 0, stream>>>(kc_c, vc, kvp, ksp);
    kv_reduce<<<196, 256, 0, stream>>>(kvp, ksp, kvb, ksum);

    // attention apply + 3 expansion MLPs fused -> attn_out (kbuf)
    attn_exp<<<dim3(N_ / 4, H_), 256, 0, stream>>>(q16, kvb, ksum,
                                                   eW, eb, eg, ebe, kbuf);

    // attn_out -> bf16, final projection + bias
    conv_f32_bf16<<<(int)(SB / 4 / 256), 256, 0, stream>>>(kbuf, ao16);
    gemm_out<<<dim3(6, 32), 256, 0, stream>>>(ao16, WoT, bo, ob);
  }
}

// Round 4
// 1839.242 us; speedup vs baseline: 3.1735x; 1.7397x over previous
//
#include <hip/hip_runtime.h>
#include <math.h>

#define B_   8
#define N_   4096
#define DIM_ 768
#define H_   12
#define D_   64

typedef unsigned short ushort_t;
typedef unsigned int uint_t;
typedef __attribute__((ext_vector_type(8))) short short8;
typedef __attribute__((ext_vector_type(4))) float f32x4;

// ---------------------------------------------------------------------------
// helpers
// ---------------------------------------------------------------------------
__device__ __forceinline__ float gelu_exact(float z) {
  return 0.5f * z * (1.f + erff(z * 0.70710678118654752440f));
}

__device__ __forceinline__ ushort_t f2bf(float f) {
  union { float f; unsigned u; } x; x.f = f;
  unsigned r = x.u + 0x7FFFu + ((x.u >> 16) & 1u);   // RNE
  return (ushort_t)(r >> 16);
}

__device__ __forceinline__ float bf2f(ushort_t h) {
  union { unsigned u; float f; } x; x.u = ((unsigned)h) << 16;
  return x.f;
}

__device__ __forceinline__ void gl_lds16(const ushort_t* g, ushort_t* l) {
  __builtin_amdgcn_global_load_lds(
      (const __attribute__((address_space(1))) void*)g,
      (__attribute__((address_space(3))) void*)l, 16, 0, 0);
}

// ---------------------------------------------------------------------------
// 768x768 fp32 -> bf16 transposed copy (dst[n][k] = src[k][n])
// ---------------------------------------------------------------------------
__global__ __launch_bounds__(256) void transpose_w_bf16(
    const float* __restrict__ src, ushort_t* __restrict__ dst)
{
  __shared__ float t[32][33];
  const int lx = threadIdx.x & 31, ly = threadIdx.x >> 5;
  const int bx = blockIdx.x * 32;
  const int by = blockIdx.y * 32;
  #pragma unroll
  for (int j = 0; j < 32; j += 8)
    t[ly + j][lx] = src[(size_t)(by + ly + j) * 768 + bx + lx];
  __syncthreads();
  #pragma unroll
  for (int j = 0; j < 32; j += 8)
    dst[(size_t)(bx + ly + j) * 768 + by + lx] = f2bf(t[lx][ly + j]);
}

// 6x 64x64 transpose to bf16: dst[m][c][d] = src_m[d][c]; m<3 pool, else exp
__global__ __launch_bounds__(256) void transpose64_bf16(
    const float* __restrict__ pW, const float* __restrict__ eW,
    ushort_t* __restrict__ dst)
{
  const int m = blockIdx.x;
  const float* src = (m < 3) ? (pW + m * 4096) : (eW + (m - 3) * 4096);
  ushort_t* o = dst + m * 4096;
  for (int i = threadIdx.x; i < 4096; i += 256) {
    const int r = i >> 6, c = i & 63;
    o[c * 64 + r] = f2bf(src[r * 64 + c]);
  }
}

__global__ __launch_bounds__(256) void conv_f32_bf16(
    const float* __restrict__ src, ushort_t* __restrict__ dst)
{
  const int i = blockIdx.x * 256 + threadIdx.x;
  float4 f = ((const float4*)src)[i];
  ushort4 o;
  o.x = f2bf(f.x); o.y = f2bf(f.y); o.z = f2bf(f.z); o.w = f2bf(f.w);
  ((ushort4*)dst)[i] = o;
}

// ---------------------------------------------------------------------------
// bf16 MFMA GEMM mainloop: 128x128 tile, BK=32, 4 waves 2x2, 4x4 16x16 each
// ---------------------------------------------------------------------------
#define GEMM_MAINLOOP(A, Bt, K)                                               \
  __shared__ ushort_t As[128 * 32];                                           \
  __shared__ ushort_t Bs[128 * 32];                                           \
  const int tid = threadIdx.x;                                                \
  const int row0 = blockIdx.y * 128;                                          \
  const int col0 = blockIdx.x * 128;                                          \
  const int sr = tid >> 2;                                                    \
  const int sk = (tid & 3) * 8;                                               \
  const ushort_t* Ag0 = (A) + (size_t)(row0 + sr) * (K) + sk;                 \
  const ushort_t* Ag1 = Ag0 + (size_t)64 * (K);                               \
  const ushort_t* Bg0 = (Bt) + (size_t)(col0 + sr) * (K) + sk;                \
  const ushort_t* Bg1 = Bg0 + (size_t)64 * (K);                               \
  ushort_t* Asw = As + (tid >> 6) * 512;                                      \
  ushort_t* Bsw = Bs + (tid >> 6) * 512;                                      \
  const int w = tid >> 6, lane = tid & 63;                                    \
  const int wm = w >> 1, wn = w & 1;                                          \
  const int qd = lane >> 4, l15 = lane & 15;                                  \
  const int aoff = (wm * 64 + l15) * 32 + qd * 8;                             \
  const int boff = (wn * 64 + l15) * 32 + qd * 8;                             \
  f32x4 acc[4][4] = {};                                                       \
  for (int k0 = 0; k0 < (K); k0 += 32) {                                      \
    __syncthreads();                                                          \
    gl_lds16(Ag0 + k0, Asw);                                                  \
    gl_lds16(Ag1 + k0, Asw + 2048);                                           \
    gl_lds16(Bg0 + k0, Bsw);                                                  \
    gl_lds16(Bg1 + k0, Bsw + 2048);                                           \
    __syncthreads();                                                          \
    short8 af[4], bfr[4];                                                     \
    _Pragma("unroll")                                                         \
    for (int mt = 0; mt < 4; ++mt) af[mt] = *(const short8*)&As[aoff + mt * 512]; \
    _Pragma("unroll")                                                         \
    for (int nt = 0; nt < 4; ++nt) bfr[nt] = *(const short8*)&Bs[boff + nt * 512]; \
    _Pragma("unroll")                                                         \
    for (int mt = 0; mt < 4; ++mt)                                            \
      _Pragma("unroll")                                                       \
      for (int nt = 0; nt < 4; ++nt)                                          \
        acc[mt][nt] = __builtin_amdgcn_mfma_f32_16x16x32_bf16(                \
            af[mt], bfr[nt], acc[mt][nt], 0, 0, 0);                           \
  }

// QKV: q bf16 elu+1, k bf16 elu+1, v f32. grid (18, 32)
__global__ __launch_bounds__(256) void gemm_qkv(
    const ushort_t* __restrict__ A, const ushort_t* __restrict__ Bt,
    ushort_t* __restrict__ qo, ushort_t* __restrict__ ko, float* __restrict__ vo)
{
  GEMM_MAINLOOP(A, Bt, 768)
  const int sel = col0 / 768;
  const int colbase = (col0 % 768) + wn * 64;
  #pragma unroll
  for (int mt = 0; mt < 4; ++mt) {
    #pragma unroll
    for (int nt = 0; nt < 4; ++nt) {
      const int cg = colbase + nt * 16 + l15;
      #pragma unroll
      for (int r = 0; r < 4; ++r) {
        const int rg = row0 + wm * 64 + mt * 16 + qd * 4 + r;
        const float vv = acc[mt][nt][r];
        if (sel == 0) {
          const float e = (vv > 0.f) ? vv + 1.f : expf(vv);
          qo[(size_t)rg * 768 + cg] = f2bf(e);
        } else if (sel == 1) {
          const float e = (vv > 0.f) ? vv + 1.f : expf(vv);
          ko[(size_t)rg * 768 + cg] = f2bf(e);
        } else {
          vo[(size_t)rg * 768 + cg] = vv;
        }
      }
    }
  }
}

// Output GEMM + bias. grid (6, 32)
__global__ __launch_bounds__(256) void gemm_out(
    const ushort_t* __restrict__ A, const ushort_t* __restrict__ Bt,
    const float* __restrict__ bo, float* __restrict__ C)
{
  GEMM_MAINLOOP(A, Bt, 768)
  #pragma unroll
  for (int mt = 0; mt < 4; ++mt) {
    #pragma unroll
    for (int nt = 0; nt < 4; ++nt) {
      const int cg = col0 + wn * 64 + nt * 16 + l15;
      #pragma unroll
      for (int r = 0; r < 4; ++r) {
        const int rg = row0 + wm * 64 + mt * 16 + qd * 4 + r;
        C[(size_t)rg * 768 + cg] = acc[mt][nt][r] + bo[cg];
      }
    }
  }
}

// ---------------------------------------------------------------------------
// MFMA pool stage: t = mean(in[2n],in[2n+1]); out = gelu(LN(t@W+b)*g+be)
// 128 out-tokens/block, 4 waves (wave w: rows w*32..+31). grid (n_out/128, 12)
// in bf16 addressed in[h*h_stride + n*ts + d]; out bf16 [h][n_out][64]
// ---------------------------------------------------------------------------
__global__ __launch_bounds__(256) void pool_mfma(
    const ushort_t* __restrict__ in, ushort_t* __restrict__ out,
    int n_out, long h_stride, int ts,
    const ushort_t* __restrict__ Wt, const float* __restrict__ bias,
    const float* __restrict__ g, const float* __restrict__ be)
{
  __shared__ ushort_t Wl[64 * 72];    // W^T rows padded to 72
  __shared__ ushort_t tl[128 * 72];   // pooled input, A-layout rows
  const int tid = threadIdx.x;
  const int h = blockIdx.y;
  const int row0 = blockIdx.x * 128;

  {
    const uint_t* ws = (const uint_t*)Wt;
    for (int i = tid; i < 2048; i += 256) {
      const int r = i >> 5, c = i & 31;
      ((uint_t*)(Wl + r * 72))[c] = ws[i];
    }
  }
  #pragma unroll
  for (int j = 0; j < 4; ++j) {
    const int idx = j * 256 + tid;
    const int rl = idx >> 3, ch = idx & 7;
    const ushort_t* p = in + (size_t)h * h_stride + (size_t)(2 * (row0 + rl)) * ts + ch * 8;
    short8 a = *(const short8*)p;
    short8 b2 = *(const short8*)(p + ts);
    short8 o;
    #pragma unroll
    for (int e = 0; e < 8; ++e)
      o[e] = (short)f2bf(0.5f * (bf2f((ushort_t)a[e]) + bf2f((ushort_t)b2[e])));
    *(short8*)&tl[rl * 72 + ch * 8] = o;
  }
  __syncthreads();

  const int w = tid >> 6, lane = tid & 63;
  const int quad = lane >> 4, l15 = lane & 15;

  float bv[4], gv[4], bev[4];
  #pragma unroll
  for (int nt = 0; nt < 4; ++nt) {
    const int c = nt * 16 + l15;
    bv[nt] = bias[c]; gv[nt] = g[c]; bev[nt] = be[c];
  }
  f32x4 a2[2][4];
  #pragma unroll
  for (int mt = 0; mt < 2; ++mt)
    #pragma unroll
    for (int nt = 0; nt < 4; ++nt)
      a2[mt][nt] = f32x4{bv[nt], bv[nt], bv[nt], bv[nt]};

  #pragma unroll
  for (int ks = 0; ks < 2; ++ks) {
    short8 af[2], bfr[4];
    #pragma unroll
    for (int mt = 0; mt < 2; ++mt)
      af[mt] = *(const short8*)&tl[(w * 32 + mt * 16 + l15) * 72 + ks * 32 + quad * 8];
    #pragma unroll
    for (int nt = 0; nt < 4; ++nt)
      bfr[nt] = *(const short8*)&Wl[(nt * 16 + l15) * 72 + ks * 32 + quad * 8];
    #pragma unroll
    for (int mt = 0; mt < 2; ++mt)
      #pragma unroll
      for (int nt = 0; nt < 4; ++nt)
        a2[mt][nt] = __builtin_amdgcn_mfma_f32_16x16x32_bf16(af[mt], bfr[nt], a2[mt][nt], 0, 0, 0);
  }

  #pragma unroll
  for (int mt = 0; mt < 2; ++mt)
    #pragma unroll
    for (int r = 0; r < 4; ++r) {
      float sum = a2[mt][0][r] + a2[mt][1][r] + a2[mt][2][r] + a2[mt][3][r];
      #pragma unroll
      for (int m = 1; m < 16; m <<= 1) sum += __shfl_xor(sum, m, 64);
      const float mu = sum * 0.015625f;
      float dv[4], var = 0.f;
      #pragma unroll
      for (int nt = 0; nt < 4; ++nt) { dv[nt] = a2[mt][nt][r] - mu; var += dv[nt] * dv[nt]; }
      #pragma unroll
      for (int m = 1; m < 16; m <<= 1) var += __shfl_xor(var, m, 64);
      const float rstd = rsqrtf(var * 0.015625f + 1e-5f);
      const int rg = row0 + w * 32 + mt * 16 + quad * 4 + r;
      #pragma unroll
      for (int nt = 0; nt < 4; ++nt) {
        const float z = dv[nt] * rstd * gv[nt] + bev[nt];
        out[((size_t)h * n_out + rg) * 64 + nt * 16 + l15] = f2bf(gelu_exact(z));
      }
    }
}

// ---------------------------------------------------------------------------
// V-path: mean of 8 tokens. v f32 (n,768) -> vc f32 [12][512][64]
// ---------------------------------------------------------------------------
__global__ __launch_bounds__(256) void avgpool8_v(
    const float* __restrict__ v, float* __restrict__ out)
{
  const int idx = blockIdx.x * 256 + threadIdx.x;
  const int e = idx & 63;
  const int n = (idx >> 6) & 511;
  const int h = idx >> 15;
  const float* p = v + (size_t)(8 * n) * 768 + h * 64 + e;
  float s = 0.f;
  #pragma unroll
  for (int j = 0; j < 8; ++j) s += p[(size_t)j * 768];
  out[idx] = 0.125f * s;
}

// ---------------------------------------------------------------------------
// kv partials over 32-token chunks: kc bf16, vc f32
// ---------------------------------------------------------------------------
__global__ __launch_bounds__(256) void kv_part_kernel(
    const ushort_t* __restrict__ kc, const float* __restrict__ vc,
    float* __restrict__ kvp, float* __restrict__ ksp)
{
  __shared__ float ks[32 * 64];
  __shared__ float vs[32 * 64];
  const int tid = threadIdx.x;
  const int h = blockIdx.x;
  const int c = blockIdx.y;
  const ushort_t* kp = kc + ((size_t)h * 512 + c * 32) * 64;
  const float* vp = vc + ((size_t)h * 512 + c * 32) * 64;
  #pragma unroll
  for (int i = 0; i < 2; ++i) {
    ushort4 u = ((const ushort4*)kp)[tid + 256 * i];
    float4 f; f.x = bf2f(u.x); f.y = bf2f(u.y); f.z = bf2f(u.z); f.w = bf2f(u.w);
    ((float4*)ks)[tid + 256 * i] = f;
    ((float4*)vs)[tid + 256 * i] = ((const float4*)vp)[tid + 256 * i];
  }
  __syncthreads();

  const int e = tid & 63;
  const int dg = tid >> 6;
  float acc[16] = {};
  float accs = 0.f;
  for (int nn = 0; nn < 32; ++nn) {
    const float vv = vs[nn * 64 + e];
    #pragma unroll
    for (int j = 0; j < 16; ++j)
      acc[j] += ks[nn * 64 + dg * 16 + j] * vv;
    if (tid < 64) accs += ks[nn * 64 + tid];
  }
  float* o = kvp + ((size_t)h * 16 + c) * 4096;
  #pragma unroll
  for (int j = 0; j < 16; ++j)
    o[(dg * 16 + j) * 64 + e] = acc[j];
  if (tid < 64) ksp[(h * 16 + c) * 64 + tid] = accs;
}

// reduce partials -> kvxT bf16 [h][80][64]: rows 0..63 = kv^T (e,d),
// row 64 = ksum, rows 65..79 = 0. grid 240.
__global__ __launch_bounds__(256) void kv_reduce_t(
    const float* __restrict__ kvp, const float* __restrict__ ksp,
    ushort_t* __restrict__ kvxT)
{
  const int idx = blockIdx.x * 256 + threadIdx.x;   // < 61440
  const int h = idx / 5120;
  const int rem = idx - h * 5120;
  const int er = rem >> 6, d = rem & 63;
  const float scale = 0.044194173824159216f;  // 1/sqrt(512)
  float val = 0.f;
  if (er < 64) {
    float s = 0.f;
    #pragma unroll
    for (int c = 0; c < 16; ++c) s += kvp[((size_t)h * 16 + c) * 4096 + d * 64 + er];
    val = s * scale;
  } else if (er == 64) {
    float s = 0.f;
    #pragma unroll
    for (int c = 0; c < 16; ++c) s += ksp[(h * 16 + c) * 64 + d];
    val = s * scale;
  }
  kvxT[idx] = f2bf(val);
}

// ---------------------------------------------------------------------------
// Fused MFMA attention-apply + 3 expansion MLPs.
// grid (32, 12): 128 tokens x 1 head per block. Writes bf16 (n,768).
// C(128x80) = q(128x64) @ kvx(64x80); col 64 = q.ksum (denominator).
// ---------------------------------------------------------------------------
__global__ __launch_bounds__(256) void attn_exp_mfma(
    const ushort_t* __restrict__ q16, const ushort_t* __restrict__ kvxT,
    const ushort_t* __restrict__ eWt,
    const float* __restrict__ eb, const float* __restrict__ eg,
    const float* __restrict__ ebe, ushort_t* __restrict__ out16)
{
  __shared__ ushort_t kvl[80 * 72];
  __shared__ ushort_t Wl[3 * 64 * 72];
  __shared__ ushort_t tl[128 * 72];
  const int tid = threadIdx.x;
  const int h = blockIdx.y;
  const int row0 = blockIdx.x * 128;

  {
    const uint_t* src = (const uint_t*)(kvxT + (size_t)h * 5120);
    for (int i = tid; i < 2560; i += 256) {
      const int r = i >> 5, c = i & 31;
      ((uint_t*)(kvl + r * 72))[c] = src[i];
    }
    const uint_t* ws = (const uint_t*)eWt;
    for (int i = tid; i < 6144; i += 256) {
      const int s = i >> 11, rem = i & 2047, r = rem >> 5, c = rem & 31;
      ((uint_t*)(Wl + (s * 64 + r) * 72))[c] = ws[i];
    }
  }
  __syncthreads();

  const int w = tid >> 6, lane = tid & 63;
  const int quad = lane >> 4, l15 = lane & 15;

  // attention matmul incl. denominator column
  f32x4 acc[2][5] = {};
  #pragma unroll
  for (int ks = 0; ks < 2; ++ks) {
    short8 af[2], bfr[5];
    #pragma unroll
    for (int mt = 0; mt < 2; ++mt) {
      const int rg = row0 + w * 32 + mt * 16 + l15;
      af[mt] = *(const short8*)(q16 + (size_t)rg * 768 + h * 64 + ks * 32 + quad * 8);
    }
    #pragma unroll
    for (int nt = 0; nt < 5; ++nt)
      bfr[nt] = *(const short8*)&kvl[(nt * 16 + l15) * 72 + ks * 32 + quad * 8];
    #pragma unroll
    for (int mt = 0; mt < 2; ++mt)
      #pragma unroll
      for (int nt = 0; nt < 5; ++nt)
        acc[mt][nt] = __builtin_amdgcn_mfma_f32_16x16x32_bf16(af[mt], bfr[nt], acc[mt][nt], 0, 0, 0);
  }

  float t[2][4][4];
  #pragma unroll
  for (int mt = 0; mt < 2; ++mt)
    #pragma unroll
    for (int r = 0; r < 4; ++r) {
      const float den = __shfl(acc[mt][4][r], lane & 48, 64) + 1e-6f;
      const float inv = 1.f / den;
      #pragma unroll
      for (int nt = 0; nt < 4; ++nt)
        t[mt][nt][r] = acc[mt][nt][r] * inv;
    }

  // 3 expansion stages (s = 2, 1, 0)
  for (int s = 2; s >= 0; --s) {
    __syncthreads();
    #pragma unroll
    for (int mt = 0; mt < 2; ++mt)
      #pragma unroll
      for (int nt = 0; nt < 4; ++nt)
        #pragma unroll
        for (int r = 0; r < 4; ++r)
          tl[(w * 32 + mt * 16 + quad * 4 + r) * 72 + nt * 16 + l15] = f2bf(t[mt][nt][r]);
    __syncthreads();

    float bv[4], gv[4], bev[4];
    #pragma unroll
    for (int nt = 0; nt < 4; ++nt) {
      const int c = s * 64 + nt * 16 + l15;
      bv[nt] = eb[c]; gv[nt] = eg[c]; bev[nt] = ebe[c];
    }
    f32x4 a2[2][4];
    #pragma unroll
    for (int mt = 0; mt < 2; ++mt)
      #pragma unroll
      for (int nt = 0; nt < 4; ++nt)
        a2[mt][nt] = f32x4{bv[nt], bv[nt], bv[nt], bv[nt]};

    #pragma unroll
    for (int ks = 0; ks < 2; ++ks) {
      short8 af[2], bfr[4];
      #pragma unroll
      for (int mt = 0; mt < 2; ++mt)
        af[mt] = *(const short8*)&tl[(w * 32 + mt * 16 + l15) * 72 + ks * 32 + quad * 8];
      #pragma unroll
      for (int nt = 0; nt < 4; ++nt)
        bfr[nt] = *(const short8*)&Wl[(s * 64 + nt * 16 + l15) * 72 + ks * 32 + quad * 8];
      #pragma unroll
      for (int mt = 0; mt < 2; ++mt)
        #pragma unroll
        for (int nt = 0; nt < 4; ++nt)
          a2[mt][nt] = __builtin_amdgcn_mfma_f32_16x16x32_bf16(af[mt], bfr[nt], a2[mt][nt], 0, 0, 0);
    }

    #pragma unroll
    for (int mt = 0; mt < 2; ++mt)
      #pragma unroll
      for (int r = 0; r < 4; ++r) {
        float sum = a2[mt][0][r] + a2[mt][1][r] + a2[mt][2][r] + a2[mt][3][r];
        #pragma unroll
        for (int m = 1; m < 16; m <<= 1) sum += __shfl_xor(sum, m, 64);
        const float mu = sum * 0.015625f;
        float dv[4], var = 0.f;
        #pragma unroll
        for (int nt = 0; nt < 4; ++nt) { dv[nt] = a2[mt][nt][r] - mu; var += dv[nt] * dv[nt]; }
        #pragma unroll
        for (int m = 1; m < 16; m <<= 1) var += __shfl_xor(var, m, 64);
        const float rstd = rsqrtf(var * 0.015625f + 1e-5f);
        #pragma unroll
        for (int nt = 0; nt < 4; ++nt) {
          const float z = dv[nt] * rstd * gv[nt] + bev[nt];
          t[mt][nt][r] = gelu_exact(z);
        }
      }
  }

  #pragma unroll
  for (int mt = 0; mt < 2; ++mt)
    #pragma unroll
    for (int nt = 0; nt < 4; ++nt)
      #pragma unroll
      for (int r = 0; r < 4; ++r) {
        const int rg = row0 + w * 32 + mt * 16 + quad * 4 + r;
        out16[(size_t)rg * 768 + h * 64 + nt * 16 + l15] = f2bf(t[mt][nt][r]);
      }
}

// ---------------------------------------------------------------------------
// launch
// ---------------------------------------------------------------------------
extern "C" void kernel_launch(void* const* d_in, const int* in_sizes, int n_in,
                              void* d_out, int out_size, void* d_ws, size_t ws_size,
                              hipStream_t stream)
{
  const float* x   = (const float*)d_in[0];
  const float* Wq  = (const float*)d_in[1];
  const float* Wk  = (const float*)d_in[2];
  const float* Wv  = (const float*)d_in[3];
  const float* pW  = (const float*)d_in[4];
  const float* pb  = (const float*)d_in[5];
  const float* pg  = (const float*)d_in[6];
  const float* pbe = (const float*)d_in[7];
  const float* eW  = (const float*)d_in[8];
  const float* eb  = (const float*)d_in[9];
  const float* eg  = (const float*)d_in[10];
  const float* ebe = (const float*)d_in[11];
  const float* Wo  = (const float*)d_in[12];
  const float* bo  = (const float*)d_in[13];
  float* outp = (float*)d_out;

  // ---- workspace map (bytes) ----
  unsigned char* wsb = (unsigned char*)d_ws;
  ushort_t* WqkvT = (ushort_t*)(wsb + 0);              //  3,538,944
  ushort_t* WoT   = (ushort_t*)(wsb + 3538944);        //  1,179,648
  ushort_t* Wt6   = (ushort_t*)(wsb + 4718592);        //     49,152 (3 pool + 3 exp, transposed bf16)
  ushort_t* q16   = (ushort_t*)(wsb + 4767744);        //  6,291,456
  ushort_t* xb16  = (ushort_t*)(wsb + 11059200);       //  6,291,456 (later: ao16)
  ushort_t* k16   = (ushort_t*)(wsb + 17350656);       //  6,291,456
  float*    v     = (float*)   (wsb + 23642112);       // 12,582,912 (later: kc_a/b/c)
  float*    vc    = (float*)   (wsb + 36225024);       //  1,572,864
  float*    kvp   = (float*)   (wsb + 37797888);       //  3,145,728
  float*    ksp   = (float*)   (wsb + 40943616);       //     49,152
  ushort_t* kvxT  = (ushort_t*)(wsb + 40992768);       //    122,880
  const size_t need = 41115648;
  if (ws_size < need) return;

  ushort_t* ao16 = xb16;
  ushort_t* kc_a = (ushort_t*)v;                                 // [12][2048][64] bf16
  ushort_t* kc_b = (ushort_t*)((unsigned char*)v + 3145728);     // [12][1024][64]
  ushort_t* kc_c = (ushort_t*)((unsigned char*)v + 4718592);     // [12][512][64]
  const ushort_t* pWt = Wt6;
  const ushort_t* eWt = Wt6 + 3 * 4096;

  const size_t SB = (size_t)N_ * DIM_;

  transpose_w_bf16<<<dim3(24, 24), 256, 0, stream>>>(Wq, WqkvT);
  transpose_w_bf16<<<dim3(24, 24), 256, 0, stream>>>(Wk, WqkvT + 768 * 768);
  transpose_w_bf16<<<dim3(24, 24), 256, 0, stream>>>(Wv, WqkvT + 2 * 768 * 768);
  transpose_w_bf16<<<dim3(24, 24), 256, 0, stream>>>(Wo, WoT);
  transpose64_bf16<<<6, 256, 0, stream>>>(pW, eW, Wt6);

  for (int b = 0; b < B_; ++b) {
    const float* xb = x + (size_t)b * SB;
    float* ob = outp + (size_t)b * SB;

    conv_f32_bf16<<<(int)(SB / 4 / 256), 256, 0, stream>>>(xb, xb16);
    gemm_qkv<<<dim3(18, 32), 256, 0, stream>>>(xb16, WqkvT, q16, k16, v);

    avgpool8_v<<<1536, 256, 0, stream>>>(v, vc);

    // k-path pooling (MFMA), output [h][n][64] bf16
    pool_mfma<<<dim3(16, 12), 256, 0, stream>>>(k16, kc_a, 2048, 64L, 768,
                                                pWt, pb, pg, pbe);
    pool_mfma<<<dim3(8, 12), 256, 0, stream>>>(kc_a, kc_b, 1024, 2048L * 64, 64,
                                               pWt + 4096, pb + 64, pg + 64, pbe + 64);
    pool_mfma<<<dim3(4, 12), 256, 0, stream>>>(kc_b, kc_c, 512, 1024L * 64, 64,
                                               pWt + 8192, pb + 128, pg + 128, pbe + 128);

    kv_part_kernel<<<dim3(12, 16), 256, 0, stream>>>(kc_c, vc, kvp, ksp);
    kv_reduce_t<<<240, 256, 0, stream>>>(kvp, ksp, kvxT);

    attn_exp_mfma<<<dim3(32, 12), 256, 0, stream>>>(q16, kvxT, eWt,
                                                    eb, eg, ebe, ao16);

    gemm_out<<<dim3(6, 32), 256, 0, stream>>>(ao16, WoT, bo, ob);
  }
}